// Round 4
// baseline (157.879 us; speedup 1.0000x reference)
//
#include <hip/hip_runtime.h>

// ---------------------------------------------------------------------------
// QuantumQKGenerator, fully fused (R7): out[b] = expectations of
// S = QFT * U_circuit * normalize(x[b]).
//
// R6 post-mortem: gemm (42.5us, 808 TF) hit the 128^2-structure ceiling.
// Instead of porting the 8-phase GEMM template, exploit structure: W is a
// product of butterflies, so apply it per-row directly:
//   - one WAVE per batch row; lane l holds amps k = l*16+i (float2 c[16])
//   - layers RX/RY/RZ fused per-wire into one 2x2 unitary M = Mz*My*Mx
//   - gates on k-bits 0..3: intra-lane register math
//   - gates on k-bits 4..9: shfl_xor partner exchange
//   - CNOT ring + bit-reversal: ONE wave-local LDS gather (R5's verified
//     composed permutation), no barrier (wave-private scratch)
//   - 1024-pt DIT FFT: 4 intra-lane + 6 cross-lane (shfl) radix-2 stages,
//     positive twiddles (R0/R5-verified convention), 1/32 folded into the
//     load-time normalize scale
//   - expectations: verbatim from the verified expect_kernel (swizzled
//     wave-private LDS staging + shfl_xor butterfly reductions)
// Replaces prep+transpose+gemm+expect (4 launches, ~100 MB HBM traffic)
// with ONE kernel reading 32 MB and writing 1 MB.  fp32 end-to-end.
// ---------------------------------------------------------------------------

// 6-stage full-wave butterfly sum (all 64 lanes end with the total).
__device__ __forceinline__ float wred(float v) {
    v += __shfl_xor(v, 1);
    v += __shfl_xor(v, 2);
    v += __shfl_xor(v, 4);
    v += __shfl_xor(v, 8);
    v += __shfl_xor(v, 16);
    v += __shfl_xor(v, 32);
    return v;
}

__global__ __launch_bounds__(256) void fused_kernel(const float* __restrict__ w,
                                                    const float* __restrict__ x,
                                                    float* __restrict__ out)
{
    __shared__ float uu[10][8];                    // combined Mz*My*Mx per wire
    __shared__ float ryc[10], rys[10];             // layer-3 RY coefficients
    __shared__ __align__(16) float scr[4][2048];   // per-wave scratch (8 KB)
    const int tid = threadIdx.x;
    const int wv = tid >> 6, l = tid & 63;
    const int row = blockIdx.x * 4 + wv;
    float* bw = scr[wv];

    // ---- per-block setup: combined single-qubit unitaries (uniform) ----
    if (tid < 10) {
        float t0 = w[tid*4 + 0] * 0.5f, t1 = w[tid*4 + 1] * 0.5f;
        float t2 = w[tid*4 + 2] * 0.5f, t3 = w[tid*4 + 3] * 0.5f;
        float s0, c0, s1, c1, s2, c2, s3, c3;
        __sincosf(t0, &s0, &c0);
        __sincosf(t1, &s1, &c1);
        __sincosf(t2, &s2, &c2);
        __sincosf(t3, &s3, &c3);
        // M = Mz*My*Mx (RX applied first).  Verified special cases:
        // RX-only: [[c,-is],[-is,c]]; RY-only: [[c,-s],[s,c]]; RZ-only: diag.
        uu[tid][0] =  c2*c1*c0 + s2*s1*s0;     // u00r
        uu[tid][1] =  c2*s1*s0 - s2*c1*c0;     // u00i
        uu[tid][2] = -(c2*s1*c0 + s2*c1*s0);   // u01r
        uu[tid][3] =  s2*s1*c0 - c2*c1*s0;     // u01i
        uu[tid][4] =  c2*s1*c0 + s2*c1*s0;     // u10r
        uu[tid][5] =  s2*s1*c0 - c2*c1*s0;     // u10i
        uu[tid][6] =  c2*c1*c0 + s2*s1*s0;     // u11r =  u00r
        uu[tid][7] =  s2*c1*c0 - c2*s1*s0;     // u11i = -u00i
        ryc[tid] = c3;
        rys[tid] = s3;
    }
    __syncthreads();

    // ---- load row, normalize (1/||x|| * 1/32 folded into one scale) ----
    const float* xr = x + (size_t)row * 1024 + l * 16;
    float4 v0 = ((const float4*)xr)[0];
    float4 v1 = ((const float4*)xr)[1];
    float4 v2 = ((const float4*)xr)[2];
    float4 v3 = ((const float4*)xr)[3];
    float ss = v0.x*v0.x + v0.y*v0.y + v0.z*v0.z + v0.w*v0.w
             + v1.x*v1.x + v1.y*v1.y + v1.z*v1.z + v1.w*v1.w
             + v2.x*v2.x + v2.y*v2.y + v2.z*v2.z + v2.w*v2.w
             + v3.x*v3.x + v3.y*v3.y + v3.z*v3.z + v3.w*v3.w;
    ss = wred(ss);
    const float scale = 0.03125f / fmaxf(sqrtf(ss), 1e-8f);

    float2 c[16];
    c[0]  = make_float2(v0.x*scale, 0.f); c[1]  = make_float2(v0.y*scale, 0.f);
    c[2]  = make_float2(v0.z*scale, 0.f); c[3]  = make_float2(v0.w*scale, 0.f);
    c[4]  = make_float2(v1.x*scale, 0.f); c[5]  = make_float2(v1.y*scale, 0.f);
    c[6]  = make_float2(v1.z*scale, 0.f); c[7]  = make_float2(v1.w*scale, 0.f);
    c[8]  = make_float2(v2.x*scale, 0.f); c[9]  = make_float2(v2.y*scale, 0.f);
    c[10] = make_float2(v2.z*scale, 0.f); c[11] = make_float2(v2.w*scale, 0.f);
    c[12] = make_float2(v3.x*scale, 0.f); c[13] = make_float2(v3.y*scale, 0.f);
    c[14] = make_float2(v3.z*scale, 0.f); c[15] = make_float2(v3.w*scale, 0.f);

    // ---- combined RX/RY/RZ layers: bit p <-> wire 9-p (unreversed) ----
    // intra-lane bits 0..3
    #pragma unroll
    for (int p = 0; p < 4; ++p) {
        const float* U = uu[9 - p];
        const float u00r = U[0], u00i = U[1], u01r = U[2], u01i = U[3];
        const float u10r = U[4], u10i = U[5], u11r = U[6], u11i = U[7];
        const int m = 1 << p;
        #pragma unroll
        for (int i = 0; i < 16; ++i) {
            if (i & m) continue;
            const int j = i | m;
            const float ar = c[i].x, ai = c[i].y, br = c[j].x, bi = c[j].y;
            c[i].x = u00r*ar - u00i*ai + u01r*br - u01i*bi;
            c[i].y = u00r*ai + u00i*ar + u01r*bi + u01i*br;
            c[j].x = u10r*ar - u10i*ai + u11r*br - u11i*bi;
            c[j].y = u10r*ai + u10i*ar + u11r*bi + u11i*br;
        }
    }
    // cross-lane bits 4..9 (lane-bit e): own coeff = mybit? u11:u00,
    // partner coeff = mybit? u10:u01
    #pragma unroll
    for (int e = 0; e < 6; ++e) {
        const float* U = uu[5 - e];
        const int mybit = (l >> e) & 1;
        const float car = mybit ? U[6] : U[0];
        const float cai = mybit ? U[7] : U[1];
        const float cbr = mybit ? U[4] : U[2];
        const float cbi = mybit ? U[5] : U[3];
        #pragma unroll
        for (int i = 0; i < 16; ++i) {
            const float fr = __shfl_xor(c[i].x, 1 << e);
            const float fi = __shfl_xor(c[i].y, 1 << e);
            const float ar = c[i].x, ai = c[i].y;
            c[i].x = car*ar - cai*ai + cbr*fr - cbi*fi;
            c[i].y = car*ai + cai*ar + cbr*fi + cbi*fr;
        }
    }

    // ---- CNOT ring + bit-reversal: one wave-local gather through LDS ----
    // (R5-verified composition: new[k] = old[sigma(rev(k))])
    #pragma unroll
    for (int j = 0; j < 8; ++j) {
        const int su = l*8 + (j ^ (l & 7));
        ((float4*)bw)[su] = make_float4(c[2*j].x, c[2*j].y, c[2*j+1].x, c[2*j+1].y);
    }
    #pragma unroll
    for (int i = 0; i < 16; ++i) {
        const int k = l*16 + i;
        int m = (int)(__brev((unsigned)k) >> 22);
        #pragma unroll
        for (int q = 9; q >= 0; --q) {
            const int pc = (q == 9) ? 0 : 9 - q;
            const int pt = (q == 9) ? 9 : 8 - q;
            m ^= ((m >> pc) & 1) << pt;
        }
        const int lm = m >> 4, um = (m >> 1) & 7, lo = m & 1;
        const int su = lm*8 + (um ^ (lm & 7));
        c[i] = ((const float2*)bw)[su*2 + lo];
    }

    // ---- layer-3 RY on REVERSED bits: bit p <-> wire p ----
    #pragma unroll
    for (int p = 0; p < 4; ++p) {
        const float cc = ryc[p], sv = rys[p];
        const int m = 1 << p;
        #pragma unroll
        for (int i = 0; i < 16; ++i) {
            if (i & m) continue;
            const int j = i | m;
            const float ar = c[i].x, ai = c[i].y, br = c[j].x, bi = c[j].y;
            c[i].x = cc*ar - sv*br;  c[i].y = cc*ai - sv*bi;
            c[j].x = sv*ar + cc*br;  c[j].y = sv*ai + cc*bi;
        }
    }
    #pragma unroll
    for (int e = 0; e < 6; ++e) {
        const float cc = ryc[4 + e], sv = rys[4 + e];
        const int mybit = (l >> e) & 1;
        const float sel = mybit ? sv : -sv;
        #pragma unroll
        for (int i = 0; i < 16; ++i) {
            const float fr = __shfl_xor(c[i].x, 1 << e);
            const float fi = __shfl_xor(c[i].y, 1 << e);
            c[i].x = cc*c[i].x + sel*fr;
            c[i].y = cc*c[i].y + sel*fi;
        }
    }

    // ---- 1024-pt DIT FFT (input bit-reversed, positive twiddles) ----
    // intra-lane stages 1..4 (hf = 1,2,4,8)
    #pragma unroll
    for (int st = 1; st <= 4; ++st) {
        const int hf = 1 << (st - 1);
        const float astep = 6.28318530717958647f / (float)(1 << st);
        #pragma unroll
        for (int i = 0; i < 16; ++i) {
            if (i & hf) continue;
            const int j = i | hf;
            float sw, cw;
            __sincosf(astep * (float)(i & (hf - 1)), &sw, &cw);
            const float tr = cw*c[j].x - sw*c[j].y;
            const float ti = cw*c[j].y + sw*c[j].x;
            const float ur = c[i].x, ui = c[i].y;
            c[i].x = ur + tr; c[i].y = ui + ti;
            c[j].x = ur - tr; c[j].y = ui - ti;
        }
    }
    // cross-lane stages 5..10 (lane-bit e2; j2 = (l mod 2^e2)*16 + i)
    #pragma unroll
    for (int e2 = 0; e2 < 6; ++e2) {
        const int st = 5 + e2;
        const float astep = 6.28318530717958647f / (float)(1 << st);
        const int mybit = (l >> e2) & 1;
        const float base = astep * 16.0f * (float)(l & ((1 << e2) - 1));
        #pragma unroll
        for (int i = 0; i < 16; ++i) {
            const float fr = __shfl_xor(c[i].x, 1 << e2);
            const float fi = __shfl_xor(c[i].y, 1 << e2);
            float sw, cw;
            __sincosf(base + astep * (float)i, &sw, &cw);
            // pair (a at bit0-lane, b at bit1-lane): t=w*b; a'=a+t; b'=a-t
            const float zr = mybit ? c[i].x : fr;   // b operand
            const float zi = mybit ? c[i].y : fi;
            const float tr = cw*zr - sw*zi;
            const float ti = cw*zi + sw*zr;
            const float ur = mybit ? fr : c[i].x;   // a operand
            const float ui = mybit ? fi : c[i].y;
            c[i].x = mybit ? (ur - tr) : (ur + tr);
            c[i].y = mybit ? (ui - ti) : (ui + ti);
        }
    }

    // ---- expectations (verbatim from the verified expect_kernel) ----
    #pragma unroll
    for (int j = 0; j < 8; ++j) {
        const int su = l*8 + (j ^ (l & 7));
        ((float4*)bw)[su] = make_float4(c[2*j].x, c[2*j].y, c[2*j+1].x, c[2*j+1].y);
    }

    float P2s = 0.f;
    #pragma unroll
    for (int i = 0; i < 16; ++i)
        P2s += c[i].x*c[i].x + c[i].y*c[i].y;

    float outv = 0.f;   // lane o ends up holding out[row][o]

    // intra-lane qubits: k-bit p = 0..3 -> q = 9-p
    #pragma unroll
    for (int p = 0; p < 4; ++p) {
        const int m = 1 << p;
        const int q = 9 - p;
        float rr = 0.f, ii = 0.f, zz = 0.f;
        #pragma unroll
        for (int i = 0; i < 16; ++i) {
            if (i & m) continue;
            const int j = i | m;
            rr += c[i].x*c[j].x + c[i].y*c[j].y;
            ii += c[i].x*c[j].y - c[i].y*c[j].x;
            zz += (c[i].x*c[i].x + c[i].y*c[i].y) - (c[j].x*c[j].x + c[j].y*c[j].y);
        }
        rr = wred(rr);
        ii = wred(ii);
        zz = wred(zz);
        outv = (l == q)      ? 2.f*rr : outv;
        outv = (l == 10 + q) ? 2.f*ii : outv;
        outv = (l == 20 + q) ? zz     : outv;
    }

    // cross-lane qubits: lane-bit e (k-bit 4+e) -> q = 5-e
    #pragma unroll
    for (int e = 0; e < 6; ++e) {
        const int q = 5 - e;
        const int part = l ^ (1 << e);
        const int mybit = (l >> e) & 1;
        const float sgn = mybit ? -1.f : 1.f;
        const int j0 = mybit ? 4 : 0;   // my half of the pair's units (LDS addr only)
        float rr = 0.f, ii = 0.f;
        #pragma unroll
        for (int j = 0; j < 4; ++j) {
            const int su = part*8 + ((j0 + j) ^ (part & 7));
            const float4 f = ((const float4*)bw)[su];
            const float2 a0 = c[2*j],     a1 = c[2*j + 1];
            const float2 b0 = c[2*j + 8], b1 = c[2*j + 9];
            const float m0x = mybit ? b0.x : a0.x;
            const float m0y = mybit ? b0.y : a0.y;
            const float m1x = mybit ? b1.x : a1.x;
            const float m1y = mybit ? b1.y : a1.y;
            rr += m0x*f.x + m0y*f.y;
            ii += m0x*f.y - m0y*f.x;
            rr += m1x*f.z + m1y*f.w;
            ii += m1x*f.w - m1y*f.z;
        }
        const float rr_s = wred(rr);
        const float ii_s = wred(sgn * ii);
        const float zz_s = wred(sgn * P2s);
        outv = (l == q)      ? 2.f*rr_s : outv;
        outv = (l == 10 + q) ? 2.f*ii_s : outv;
        outv = (l == 20 + q) ? zz_s     : outv;
    }

    if (l < 30)
        out[(size_t)row * 30 + l] = outv;
}

// ---------------------------------------------------------------------------
extern "C" void kernel_launch(void* const* d_in, const int* in_sizes, int n_in,
                              void* d_out, int out_size, void* d_ws, size_t ws_size,
                              hipStream_t stream) {
    const float* x = (const float*)d_in[0];   // [8192][1024]
    const float* w = (const float*)d_in[1];   // [10][4]
    float* out = (float*)d_out;               // [8192][30]
    (void)d_ws; (void)ws_size;                // workspace no longer needed

    fused_kernel<<<2048, 256, 0, stream>>>(w, x, out);
}